// Round 6
// baseline (567.431 us; speedup 1.0000x reference)
//
#include <hip/hip_runtime.h>
#include <math.h>

constexpr int MM = 10000;   // N_NODES
constexpr int DD = 256;     // D_IN == D_OUT
constexpr int EE = 320000;  // N_EDGES

// attention-matrix zero-fill partition (float4 units; total = MM*MM/4 = 25e6)
constexpr size_t ZT = (size_t)MM * MM / 4;   // 25,000,000
constexpr size_t Z1 = 8750000;               // gemm dispatch    (140 MB)
constexpr size_t Z2 = 13125000;              // dots dispatch     (70 MB)
constexpr size_t Z3 = 16250000;              // scan dispatch     (50 MB)
                                             // score dispatch: [Z3,ZT) (140 MB)

// filler: zero att4[lo,hi) using nf blocks of 256 thr, fid = filler block idx
__device__ __forceinline__ void fill_slice(float4* att4, size_t lo, size_t hi,
                                           int fid, int nf) {
    const size_t stride = (size_t)nf * 256;
    for (size_t p = lo + (size_t)fid * 256 + threadIdx.x; p < hi; p += stride)
        att4[p] = make_float4(0.f, 0.f, 0.f, 0.f);
}

// ---------------------------------------------------------------------------
// Dispatch 1: 628 GEMM work blocks + 1024 filler blocks (140 MB + deg zero).
// GEMM: H = X @ W^T (fp32), 64x64 tile, BK=16, 4x4 micro-tile.
// ---------------------------------------------------------------------------
__global__ __launch_bounds__(256) void gemm_fill(const float* __restrict__ X,
                                                 const float* __restrict__ W,
                                                 float* __restrict__ H,
                                                 float4* __restrict__ att4,
                                                 int* __restrict__ deg) {
    if (blockIdx.x >= 628) {  // filler block
        const int fid = blockIdx.x - 628;
        if (fid == 0) {  // zero deg[MM] (40 KB) — used by NEXT dispatch
            for (int i = threadIdx.x; i < MM; i += 256) deg[i] = 0;
        }
        fill_slice(att4, 0, Z1, fid, 1024);
        return;
    }
    __shared__ float xs[16][68];
    __shared__ float ws[16][68];
    const int tid = threadIdx.x;
    const int bm = (blockIdx.x % 157) << 6;
    const int bn = (blockIdx.x / 157) << 6;
    const int lr = tid >> 2;          // 0..63
    const int lc = (tid & 3) << 2;    // 0,4,8,12
    const int tx = tid & 15;
    const int ty = tid >> 4;

    float acc[4][4] = {};

    for (int k0 = 0; k0 < DD; k0 += 16) {
        const int gr = bm + lr;
        float4 xv = make_float4(0.f, 0.f, 0.f, 0.f);
        if (gr < MM) xv = *(const float4*)(X + (size_t)gr * DD + k0 + lc);
        float4 wv = *(const float4*)(W + (size_t)(bn + lr) * DD + k0 + lc);
        xs[lc + 0][lr] = xv.x; xs[lc + 1][lr] = xv.y;
        xs[lc + 2][lr] = xv.z; xs[lc + 3][lr] = xv.w;
        ws[lc + 0][lr] = wv.x; ws[lc + 1][lr] = wv.y;
        ws[lc + 2][lr] = wv.z; ws[lc + 3][lr] = wv.w;
        __syncthreads();
#pragma unroll
        for (int k = 0; k < 16; ++k) {
            float4 xr4 = *(const float4*)(&xs[k][ty << 2]);
            float4 wr4 = *(const float4*)(&ws[k][tx << 2]);
            float xr[4] = {xr4.x, xr4.y, xr4.z, xr4.w};
            float wr[4] = {wr4.x, wr4.y, wr4.z, wr4.w};
#pragma unroll
            for (int i = 0; i < 4; ++i)
#pragma unroll
                for (int j = 0; j < 4; ++j) acc[i][j] += xr[i] * wr[j];
        }
        __syncthreads();
    }
#pragma unroll
    for (int i = 0; i < 4; ++i) {
        const int r = bm + (ty << 2) + i;
        if (r < MM) {
            *(float4*)(H + (size_t)r * DD + bn + (tx << 2)) =
                make_float4(acc[i][0], acc[i][1], acc[i][2], acc[i][3]);
        }
    }
}

// ---------------------------------------------------------------------------
// Dispatch 2: 1250 work blocks (2 nodes/wave dots + 1 edge/thread deg count)
//           + 512 filler blocks (70 MB).
// ---------------------------------------------------------------------------
__global__ __launch_bounds__(256) void dots_deg_fill(const float* __restrict__ h,
                                                     const float* __restrict__ att_src,
                                                     const float* __restrict__ att_dst,
                                                     const int* __restrict__ dst,
                                                     float* __restrict__ s_src,
                                                     float* __restrict__ s_dst,
                                                     int* __restrict__ deg,
                                                     float4* __restrict__ att4) {
    if (blockIdx.x >= 1250) {  // filler block
        fill_slice(att4, Z1, Z2, blockIdx.x - 1250, 512);
        return;
    }
    const int wv = threadIdx.x >> 6, lane = threadIdx.x & 63;
    const float4 a = ((const float4*)att_src)[lane];
    const float4 b = ((const float4*)att_dst)[lane];
#pragma unroll
    for (int half = 0; half < 2; ++half) {
        const int node = blockIdx.x * 4 + wv + half * 5000;
        float4 v = ((const float4*)h)[(size_t)node * 64 + lane];
        float ds = v.x * a.x + v.y * a.y + v.z * a.z + v.w * a.w;
        float dd = v.x * b.x + v.y * b.y + v.z * b.z + v.w * b.w;
#pragma unroll
        for (int off = 32; off; off >>= 1) {
            ds += __shfl_xor(ds, off);
            dd += __shfl_xor(dd, off);
        }
        if (lane == 0) { s_src[node] = ds; s_dst[node] = dd; }
    }
    // degree counting: 1250*256 == EE exactly (1 edge per thread)
    const int e = blockIdx.x * 256 + threadIdx.x;
    atomicAdd(&deg[dst[e]], 1);
}

// ---------------------------------------------------------------------------
// Dispatch 3: block 0 = exclusive scan (256 thr, C=40) + 2048 filler (50 MB).
// ---------------------------------------------------------------------------
__global__ __launch_bounds__(256) void scan_fill(const int* __restrict__ deg,
                                                 int* __restrict__ row_off,
                                                 int* __restrict__ cursor,
                                                 float4* __restrict__ att4) {
    if (blockIdx.x >= 1) {  // filler block
        fill_slice(att4, Z2, Z3, blockIdx.x - 1, 2048);
        return;
    }
    constexpr int C = 40;  // 256*40 >= MM
    __shared__ int wsum[4];
    const int t = threadIdx.x, wv = t >> 6, lane = t & 63;
    const int i0 = t * C;
    int total = 0;
#pragma unroll 8
    for (int k = 0; k < C; ++k) { int i = i0 + k; total += (i < MM) ? deg[i] : 0; }
    int incl = total;
#pragma unroll
    for (int off = 1; off < 64; off <<= 1) {
        int u = __shfl_up(incl, off);
        if (lane >= off) incl += u;
    }
    if (lane == 63) wsum[wv] = incl;
    __syncthreads();
    if (t == 0) {
        int run = 0;
#pragma unroll
        for (int w2 = 0; w2 < 4; ++w2) { int v = wsum[w2]; wsum[w2] = run; run += v; }
    }
    __syncthreads();
    int run = wsum[wv] + incl - total;   // global exclusive prefix
#pragma unroll 8
    for (int k = 0; k < C; ++k) {
        const int i = i0 + k;
        if (i < MM) {
            const int v = deg[i];
            cursor[i] = run;
            run += v;
            row_off[i + 1] = run;
        }
    }
    if (t == 0) row_off[0] = 0;
}

// ---------------------------------------------------------------------------
// Dispatch 4: 625 work blocks (2 edges/thread: score + CSR scatter)
//           + 1024 filler blocks (140 MB).  625*512 == EE.
// ---------------------------------------------------------------------------
__global__ __launch_bounds__(256) void score_scatter_fill(
    const int* __restrict__ src, const int* __restrict__ dst,
    const float* __restrict__ s_src, const float* __restrict__ s_dst,
    float* __restrict__ score, int* __restrict__ cursor,
    int* __restrict__ csr, float4* __restrict__ att4) {
    if (blockIdx.x >= 625) {  // filler block
        fill_slice(att4, Z3, ZT, blockIdx.x - 625, 1024);
        return;
    }
#pragma unroll
    for (int half = 0; half < 2; ++half) {
        const int e = blockIdx.x * 512 + half * 256 + threadIdx.x;
        const int s = src[e], d = dst[e];
        float sc = s_src[s] + s_dst[d];
        sc = (sc >= 0.f) ? sc : 0.2f * sc;
        score[e] = sc;
        const int pos = atomicAdd(&cursor[d], 1);
        csr[pos] = e;
    }
}

// ---------------------------------------------------------------------------
// Dispatch 5: wave-per-node softmax + attention scatter + aggregation.
// (unchanged from the passing round-5 version)
// ---------------------------------------------------------------------------
__global__ __launch_bounds__(256) void node_agg(const float* __restrict__ h,
                                                const float* __restrict__ score,
                                                const int* __restrict__ src,
                                                const int* __restrict__ csr,
                                                const int* __restrict__ row_off,
                                                float* __restrict__ out,
                                                float* __restrict__ att) {
    const int wv = threadIdx.x >> 6, lane = threadIdx.x & 63;
    const int node = blockIdx.x * 4 + wv;
    if (node >= MM) return;
    const int r0 = row_off[node], r1 = row_off[node + 1];
    const float4* h4 = (const float4*)h;
    float4* out4 = (float4*)out;

    if (r0 == r1) {  // no incoming edges: keep own transformed features
        out4[(size_t)node * 64 + lane] = h4[(size_t)node * 64 + lane];
        return;
    }

    // phase 1: max (cache first 4 chunks in registers)
    int e_reg[4];
    float s_reg[4];
    float m = -INFINITY;
#pragma unroll
    for (int c = 0; c < 4; ++c) {
        const int i = r0 + c * 64 + lane;
        const bool vld = i < r1;
        const int e = vld ? csr[i] : 0;
        const float s = vld ? score[e] : -INFINITY;
        e_reg[c] = e; s_reg[c] = s;
        m = fmaxf(m, s);
    }
    for (int i = r0 + 256 + lane; i < r1; i += 64) m = fmaxf(m, score[csr[i]]);
#pragma unroll
    for (int off = 32; off; off >>= 1) m = fmaxf(m, __shfl_xor(m, off));

    // phase 2: exp + sum (s_reg becomes ex)
    float sum = 0.f;
#pragma unroll
    for (int c = 0; c < 4; ++c) {
        const int i = r0 + c * 64 + lane;
        const float ex = (i < r1) ? expf(s_reg[c] - m) : 0.f;
        s_reg[c] = ex;
        sum += ex;
    }
    for (int i = r0 + 256 + lane; i < r1; i += 64) sum += expf(score[csr[i]] - m);
#pragma unroll
    for (int off = 32; off; off >>= 1) sum += __shfl_xor(sum, off);
    const float inv = 1.f / sum;

    // phase 3: alpha scatter + shfl-broadcast aggregation (float4 channels)
    float4 acc = make_float4(0.f, 0.f, 0.f, 0.f);
#pragma unroll
    for (int c = 0; c < 4; ++c) {
        const int base = r0 + c * 64;
        if (base < r1) {
            const int i = base + lane;
            float a = 0.f; int sn = 0;
            if (i < r1) {
                a = s_reg[c] * inv;
                sn = src[e_reg[c]];
                att[(size_t)sn * MM + node] = a;
            }
            const int cnt = min(64, r1 - base);
            for (int j = 0; j < cnt; ++j) {
                const float aj = __shfl(a, j);
                const int sj = __shfl(sn, j);
                const float4 hv = h4[(size_t)sj * 64 + lane];
                acc.x += aj * hv.x; acc.y += aj * hv.y;
                acc.z += aj * hv.z; acc.w += aj * hv.w;
            }
        }
    }
    for (int base = r0 + 256; base < r1; base += 64) {  // overflow (deg>256)
        const int i = base + lane;
        float a = 0.f; int sn = 0;
        if (i < r1) {
            const int e = csr[i];
            a = expf(score[e] - m) * inv;
            sn = src[e];
            att[(size_t)sn * MM + node] = a;
        }
        const int cnt = min(64, r1 - base);
        for (int j = 0; j < cnt; ++j) {
            const float aj = __shfl(a, j);
            const int sj = __shfl(sn, j);
            const float4 hv = h4[(size_t)sj * 64 + lane];
            acc.x += aj * hv.x; acc.y += aj * hv.y;
            acc.z += aj * hv.z; acc.w += aj * hv.w;
        }
    }
    out4[(size_t)node * 64 + lane] = acc;
}

// ---------------------------------------------------------------------------
extern "C" void kernel_launch(void* const* d_in, const int* in_sizes, int n_in,
                              void* d_out, int out_size, void* d_ws, size_t ws_size,
                              hipStream_t stream) {
    const float* x       = (const float*)d_in[0];
    const float* W       = (const float*)d_in[1];
    const float* att_src = (const float*)d_in[2];
    const float* att_dst = (const float*)d_in[3];
    const int*   eidx    = (const int*)d_in[4];
    const int* src = eidx;
    const int* dst = eidx + EE;

    float* out_feat = (float*)d_out;               // [10000,256]
    float* att      = out_feat + (size_t)MM * DD;  // [10000,10000]
    float4* att4    = (float4*)att;

    float* h       = (float*)d_ws;                  // MM*DD
    float* s_src   = h + (size_t)MM * DD;           // MM
    float* s_dst   = s_src + MM;                    // MM
    float* score   = s_dst + MM;                    // EE
    int*   deg     = (int*)(score + EE);            // MM
    int*   row_off = deg + MM;                      // MM+1
    int*   cursor  = row_off + MM + 1;              // MM
    int*   csr     = cursor + MM;                   // EE

    gemm_fill<<<628 + 1024, 256, 0, stream>>>(x, W, h, att4, deg);
    dots_deg_fill<<<1250 + 512, 256, 0, stream>>>(h, att_src, att_dst, dst,
                                                  s_src, s_dst, deg, att4);
    scan_fill<<<1 + 2048, 256, 0, stream>>>(deg, row_off, cursor, att4);
    score_scatter_fill<<<625 + 1024, 256, 0, stream>>>(src, dst, s_src, s_dst,
                                                       score, cursor, csr, att4);
    node_agg<<<2500, 256, 0, stream>>>(h, score, src, csr, row_off, out_feat, att);
}